// Round 12
// baseline (33.643 us; speedup 1.0000x reference)
//
#include <hip/hip_runtime.h>
#include <stdint.h>

// Dynamic 3x3 softmax-weighted conv, reflect padding. Fused, LDS-DMA staged,
// XCD-chunked swizzle, shuffle halo, 2-band-per-block software pipeline:
// band1's DMAs issue under band0's conv + band1's softmax.
// x: (4, 64, 256, 256) f32, kernel: (4, 9, 256, 256) f32, out: (4, 64, 256, 256) f32

constexpr int BATCH = 4;
constexpr int CHAN  = 64;
constexpr int HH    = 256;
constexpr int WW    = 256;
constexpr int CG    = 4;        // channels per block
constexpr int RPB   = 4;        // output rows per band (one wave per row)
constexpr int NROW  = RPB + 2;  // staged input rows per channel per band
constexpr int NB    = 2;        // bands per block (pipelined)
constexpr int NWG   = (HH / (RPB * NB)) * (CHAN / CG) * BATCH;  // 32*16*4 = 2048
constexpr int NXCD  = 8;
constexpr int CPX   = NWG / NXCD;                               // 256 (2048%8==0)

typedef float vf4 __attribute__((ext_vector_type(4)));
typedef const __attribute__((address_space(1))) void* gas_ptr;
typedef __attribute__((address_space(3))) void* las_ptr;

__global__ __launch_bounds__(256) void dynconv_kernel(
    const float* __restrict__ x,
    const float* __restrict__ ker,
    float* __restrict__ out)
{
    __shared__ float lds[NB][CG][NROW][WW];   // 2*4*6*256*4B = 48 KiB

    // XCD-chunked bijective swizzle; hband-pair is the fastest axis so each
    // XCD sweeps contiguous rows of one (cg,b) slice.
    const int id    = blockIdx.x;
    const int work  = (id & (NXCD - 1)) * CPX + (id >> 3);
    const int hpair = work & 31;
    const int cg    = (work >> 5) & 15;
    const int b     = work >> 9;

    const int t  = threadIdx.x;
    const int rb = t >> 6;          // wave id = output row within band
    const int wq = t & 63;          // lane = float4 slot
    const int w0 = wq * 4;

    const long cs = (long)HH * WW;
    const float* xb = x   + (((long)b * CHAN + cg * CG) * cs);
    float*       ob = out + (((long)b * CHAN + cg * CG) * cs);
    const long kplane = (long)HH * WW;
    const float* kb = ker + (long)b * 9 * kplane;

    // ---- helpers ----
    auto stage_band = [&](int buf, int h0) {
        #pragma unroll
        for (int k = 0; k < (CG * NROW) / RPB; ++k) {   // 6 DMAs per wave
            const int idx  = k * RPB + rb;              // disjoint across waves
            const int ch   = idx / NROW;
            const int slot = idx % NROW;
            int g = h0 - 1 + slot;
            g = (g < 0) ? 1 : ((g > HH - 1) ? HH - 2 : g);
            const float* gsrc = xb + (long)ch * cs + (long)g * WW + w0;
            __builtin_amdgcn_global_load_lds((gas_ptr)gsrc,
                                             (las_ptr)&lds[buf][ch][slot][0], 16, 0, 0);
        }
    };

    auto softmax_row = [&](int h, float kv[9][4]) {
        const long kroff = (long)h * WW + w0;
        #pragma unroll
        for (int j = 0; j < 9; ++j) {
            const float4 v = *reinterpret_cast<const float4*>(kb + kroff + (long)j * kplane);
            kv[j][0] = v.x; kv[j][1] = v.y; kv[j][2] = v.z; kv[j][3] = v.w;
        }
        #pragma unroll
        for (int p = 0; p < 4; ++p) {
            float m = kv[0][p];
            #pragma unroll
            for (int j = 1; j < 9; ++j) m = fmaxf(m, kv[j][p]);
            float s = 0.f;
            #pragma unroll
            for (int j = 0; j < 9; ++j) { kv[j][p] = __expf(kv[j][p] - m); s += kv[j][p]; }
            const float inv = 1.0f / s;
            #pragma unroll
            for (int j = 0; j < 9; ++j) kv[j][p] *= inv;
        }
    };

    auto conv_band = [&](int buf, int h, float kv[9][4]) {
        #pragma unroll
        for (int i = 0; i < CG; ++i) {
            float acc0 = 0.f, acc1 = 0.f, acc2 = 0.f, acc3 = 0.f;
            #pragma unroll
            for (int r = 0; r < 3; ++r) {
                const float4 v = *reinterpret_cast<const float4*>(&lds[buf][i][rb + r][w0]);
                float lft = __shfl_up(v.w, 1);
                if (wq == 0)  lft = v.y;     // reflect x[-1] -> x[1]
                float rgt = __shfl_down(v.x, 1);
                if (wq == 63) rgt = v.z;     // reflect x[256] -> x[254]
                const float vals[6] = { lft, v.x, v.y, v.z, v.w, rgt };
                #pragma unroll
                for (int dx = 0; dx < 3; ++dx) {
                    const int j = r * 3 + dx;
                    acc0 = fmaf(kv[j][0], vals[0 + dx], acc0);
                    acc1 = fmaf(kv[j][1], vals[1 + dx], acc1);
                    acc2 = fmaf(kv[j][2], vals[2 + dx], acc2);
                    acc3 = fmaf(kv[j][3], vals[3 + dx], acc3);
                }
            }
            vf4 o; o.x = acc0; o.y = acc1; o.z = acc2; o.w = acc3;
            __builtin_nontemporal_store(o,
                reinterpret_cast<vf4*>(ob + (long)i * cs + (long)h * WW + w0));
        }
    };

    // ---- pipeline: stage0 | softmax0 | sync | stage1 | conv0 | softmax1 | sync | conv1 ----
    const int h0a = (hpair * NB + 0) * RPB;
    const int h0b = (hpair * NB + 1) * RPB;
    const int ha  = h0a + rb;
    const int hb  = h0b + rb;

    float kvA[9][4], kvB[9][4];

    stage_band(0, h0a);          // band0 DMAs in flight
    softmax_row(ha, kvA);        // overlaps band0 DMA latency
    __syncthreads();             // buf0 ready

    stage_band(1, h0b);          // band1 DMAs in flight under band0 compute
    conv_band(0, ha, kvA);
    softmax_row(hb, kvB);        // covers band1 DMA tail
    __syncthreads();             // buf1 ready

    conv_band(1, hb, kvB);
}

extern "C" void kernel_launch(void* const* d_in, const int* in_sizes, int n_in,
                              void* d_out, int out_size, void* d_ws, size_t ws_size,
                              hipStream_t stream) {
    const float* x   = (const float*)d_in[0];
    const float* ker = (const float*)d_in[1];
    float* out = (float*)d_out;

    dynconv_kernel<<<dim3(NWG), dim3(256), 0, stream>>>(x, ker, out);
}

// Round 13
// 30.763 us; speedup vs baseline: 1.0936x; 1.0936x over previous
//
#include <hip/hip_runtime.h>
#include <stdint.h>

// Dynamic 3x3 softmax-weighted conv, reflect padding. Barrier-free variant:
// register-held rows (no LDS, no __syncthreads), shuffle halo,
// XCD-chunked block swizzle, nontemporal stores.
// x: (4, 64, 256, 256) f32, kernel: (4, 9, 256, 256) f32, out: (4, 64, 256, 256) f32

constexpr int BATCH = 4;
constexpr int CHAN  = 64;
constexpr int HH    = 256;
constexpr int WW    = 256;
constexpr int CG    = 4;        // channels per block
constexpr int RPB   = 4;        // output rows per block (one wave per row)
constexpr int NWG   = (HH / RPB) * (CHAN / CG) * BATCH;  // 4096
constexpr int NXCD  = 8;
constexpr int CPX   = NWG / NXCD;                        // 512 (4096%8==0)

typedef float vf4 __attribute__((ext_vector_type(4)));

__global__ __launch_bounds__(256) void dynconv_kernel(
    const float* __restrict__ x,
    const float* __restrict__ ker,
    float* __restrict__ out)
{
    // XCD-chunked bijective swizzle, hband fastest: each XCD sweeps
    // contiguous rows of one (cg,b) slice.
    const int id    = blockIdx.x;
    const int work  = (id & (NXCD - 1)) * CPX + (id >> 3);
    const int hband = work & 63;
    const int cg    = (work >> 6) & 15;
    const int b     = work >> 10;

    const int t  = threadIdx.x;
    const int rb = t >> 6;          // wave id = output row in band
    const int wq = t & 63;          // lane = float4 slot
    const int w0 = wq * 4;
    const int h  = hband * RPB + rb;

    // ---- softmax over the 9 taps for this thread's 4 pixels ----
    float kv[9][4];
    const long kbase = (((long)b * 9) * HH + h) * WW + w0;
    #pragma unroll
    for (int j = 0; j < 9; ++j) {
        const float4 v = *reinterpret_cast<const float4*>(ker + kbase + (long)j * HH * WW);
        kv[j][0] = v.x; kv[j][1] = v.y; kv[j][2] = v.z; kv[j][3] = v.w;
    }
    #pragma unroll
    for (int p = 0; p < 4; ++p) {
        float m = kv[0][p];
        #pragma unroll
        for (int j = 1; j < 9; ++j) m = fmaxf(m, kv[j][p]);
        float s = 0.f;
        #pragma unroll
        for (int j = 0; j < 9; ++j) { kv[j][p] = __expf(kv[j][p] - m); s += kv[j][p]; }
        const float inv = 1.0f / s;
        #pragma unroll
        for (int j = 0; j < 9; ++j) kv[j][p] *= inv;
    }

    // ---- reflect row indices (pad=1, 'reflect': -1 -> 1, N -> N-2) ----
    const int hm = (h == 0)      ? 1      : h - 1;
    const int hp = (h == HH - 1) ? HH - 2 : h + 1;
    const int rows[3] = { hm, h, hp };

    const long cs = (long)HH * WW;
    const float* xb = x   + (((long)b * CHAN + cg * CG) * cs);
    float*       ob = out + (((long)b * CHAN + cg * CG) * cs);

    // ---- fully unrolled over CG channels; halo via cross-lane shuffle ----
    #pragma unroll
    for (int i = 0; i < CG; ++i) {
        float acc0 = 0.f, acc1 = 0.f, acc2 = 0.f, acc3 = 0.f;
        #pragma unroll
        for (int r = 0; r < 3; ++r) {
            const long rbase = (long)i * cs + (long)rows[r] * WW;
            const float4 v = *reinterpret_cast<const float4*>(xb + rbase + w0);
            float lft = __shfl_up(v.w, 1);
            if (wq == 0)  lft = v.y;     // reflect x[-1] -> x[1]
            float rgt = __shfl_down(v.x, 1);
            if (wq == 63) rgt = v.z;     // reflect x[256] -> x[254]
            const float vals[6] = { lft, v.x, v.y, v.z, v.w, rgt };
            #pragma unroll
            for (int dx = 0; dx < 3; ++dx) {
                const int j = r * 3 + dx;
                acc0 = fmaf(kv[j][0], vals[0 + dx], acc0);
                acc1 = fmaf(kv[j][1], vals[1 + dx], acc1);
                acc2 = fmaf(kv[j][2], vals[2 + dx], acc2);
                acc3 = fmaf(kv[j][3], vals[3 + dx], acc3);
            }
        }
        vf4 o; o.x = acc0; o.y = acc1; o.z = acc2; o.w = acc3;
        __builtin_nontemporal_store(o,
            reinterpret_cast<vf4*>(ob + (long)i * cs + (long)h * WW + w0));
    }
}

extern "C" void kernel_launch(void* const* d_in, const int* in_sizes, int n_in,
                              void* d_out, int out_size, void* d_ws, size_t ws_size,
                              hipStream_t stream) {
    const float* x   = (const float*)d_in[0];
    const float* ker = (const float*)d_in[1];
    float* out = (float*)d_out;

    dynconv_kernel<<<dim3(NWG), dim3(256), 0, stream>>>(x, ker, out);
}

// Round 14
// 29.148 us; speedup vs baseline: 1.1542x; 1.0554x over previous
//
#include <hip/hip_runtime.h>
#include <stdint.h>

// Dynamic 3x3 softmax-weighted conv, reflect padding. Fused single pass,
// LDS DMA staging, XCD-chunked swizzle, shuffle halo. RPB=8 tall bands:
// 10 staged rows per 8 output rows (1.25x halo ratio vs 1.5x at RPB=4).
// x: (4, 64, 256, 256) f32, kernel: (4, 9, 256, 256) f32, out: (4, 64, 256, 256) f32

constexpr int BATCH = 4;
constexpr int CHAN  = 64;
constexpr int HH    = 256;
constexpr int WW    = 256;
constexpr int CG    = 4;        // channels per block
constexpr int RPB   = 8;        // output rows per block (one wave per row)
constexpr int NROW  = RPB + 2;  // staged input rows per channel
constexpr int NWG   = (HH / RPB) * (CHAN / CG) * BATCH;  // 32*16*4 = 2048
constexpr int NXCD  = 8;
constexpr int CPX   = NWG / NXCD;                        // 256 (2048%8==0)

typedef float vf4 __attribute__((ext_vector_type(4)));
typedef const __attribute__((address_space(1))) void* gas_ptr;
typedef __attribute__((address_space(3))) void* las_ptr;

__global__ __launch_bounds__(512) void dynconv_kernel(
    const float* __restrict__ x,
    const float* __restrict__ ker,
    float* __restrict__ out)
{
    __shared__ float lds[CG][NROW][WW];   // 4*10*256*4B = 40 KiB

    // XCD-chunked bijective swizzle, hband fastest: each XCD sweeps
    // contiguous rows of one (cg,b) slice.
    const int id    = blockIdx.x;
    const int work  = (id & (NXCD - 1)) * CPX + (id >> 3);
    const int hband = work & 31;
    const int cg    = (work >> 5) & 15;
    const int b     = work >> 9;

    const int t  = threadIdx.x;
    const int rb = t >> 6;          // wave id = output row in band, 0..7
    const int wq = t & 63;          // lane = float4 slot
    const int w0 = wq * 4;
    const int h0 = hband * RPB;
    const int h  = h0 + rb;

    const long cs = (long)HH * WW;
    const float* xb = x   + (((long)b * CHAN + cg * CG) * cs);
    float*       ob = out + (((long)b * CHAN + cg * CG) * cs);

    // ---- issue all 40 row-DMAs (5 per wave), zero VGPR held ----
    #pragma unroll
    for (int k = 0; k < (CG * NROW) / RPB; ++k) {   // 5 iterations
        const int idx  = k * RPB + rb;              // 0..39, disjoint across waves
        const int ch   = idx / NROW;
        const int slot = idx % NROW;
        int g = h0 - 1 + slot;
        g = (g < 0) ? 1 : ((g > HH - 1) ? HH - 2 : g);
        const float* gsrc = xb + (long)ch * cs + (long)g * WW + w0;
        __builtin_amdgcn_global_load_lds((gas_ptr)gsrc, (las_ptr)&lds[ch][slot][0], 16, 0, 0);
    }

    // ---- kernel loads + softmax overlap the DMA latency ----
    float kv[9][4];
    const long kbase = (((long)b * 9) * HH + h) * WW + w0;
    #pragma unroll
    for (int j = 0; j < 9; ++j) {
        const float4 v = *reinterpret_cast<const float4*>(ker + kbase + (long)j * HH * WW);
        kv[j][0] = v.x; kv[j][1] = v.y; kv[j][2] = v.z; kv[j][3] = v.w;
    }
    #pragma unroll
    for (int p = 0; p < 4; ++p) {
        float m = kv[0][p];
        #pragma unroll
        for (int j = 1; j < 9; ++j) m = fmaxf(m, kv[j][p]);
        float s = 0.f;
        #pragma unroll
        for (int j = 0; j < 9; ++j) { kv[j][p] = __expf(kv[j][p] - m); s += kv[j][p]; }
        const float inv = 1.0f / s;
        #pragma unroll
        for (int j = 0; j < 9; ++j) kv[j][p] *= inv;
    }

    __syncthreads();   // drains DMA, rows visible across waves

    // ---- conv from LDS; halo via cross-lane shuffle (no bank conflicts) ----
    #pragma unroll
    for (int i = 0; i < CG; ++i) {
        float acc0 = 0.f, acc1 = 0.f, acc2 = 0.f, acc3 = 0.f;
        #pragma unroll
        for (int r = 0; r < 3; ++r) {
            const float4 v = *reinterpret_cast<const float4*>(&lds[i][rb + r][w0]);
            float lft = __shfl_up(v.w, 1);
            if (wq == 0)  lft = v.y;     // reflect x[-1] -> x[1]
            float rgt = __shfl_down(v.x, 1);
            if (wq == 63) rgt = v.z;     // reflect x[256] -> x[254]
            const float vals[6] = { lft, v.x, v.y, v.z, v.w, rgt };
            #pragma unroll
            for (int dx = 0; dx < 3; ++dx) {
                const int j = r * 3 + dx;
                acc0 = fmaf(kv[j][0], vals[0 + dx], acc0);
                acc1 = fmaf(kv[j][1], vals[1 + dx], acc1);
                acc2 = fmaf(kv[j][2], vals[2 + dx], acc2);
                acc3 = fmaf(kv[j][3], vals[3 + dx], acc3);
            }
        }
        vf4 o; o.x = acc0; o.y = acc1; o.z = acc2; o.w = acc3;
        __builtin_nontemporal_store(o,
            reinterpret_cast<vf4*>(ob + (long)i * cs + (long)h * WW + w0));
    }
}

extern "C" void kernel_launch(void* const* d_in, const int* in_sizes, int n_in,
                              void* d_out, int out_size, void* d_ws, size_t ws_size,
                              hipStream_t stream) {
    const float* x   = (const float*)d_in[0];
    const float* ker = (const float*)d_in[1];
    float* out = (float*)d_out;

    dynconv_kernel<<<dim3(NWG), dim3(512), 0, stream>>>(x, ker, out);
}

// Round 15
// 27.920 us; speedup vs baseline: 1.2050x; 1.0440x over previous
//
#include <hip/hip_runtime.h>
#include <stdint.h>

// Dynamic 3x3 softmax-weighted conv, reflect padding. Fused single pass,
// LDS DMA staging, XCD-chunked swizzle, shuffle halo.
// KEY FIX vs r11: ker loads are issued BEFORE the row-DMAs. vmcnt retires
// in order, so softmax's wait on ker data no longer drains the 24 DMAs —
// the DMAs stay in flight under the softmax VALU chain.
// x: (4, 64, 256, 256) f32, kernel: (4, 9, 256, 256) f32, out: (4, 64, 256, 256) f32

constexpr int BATCH = 4;
constexpr int CHAN  = 64;
constexpr int HH    = 256;
constexpr int WW    = 256;
constexpr int CG    = 4;        // channels per block
constexpr int RPB   = 4;        // output rows per block (one wave per row)
constexpr int NROW  = RPB + 2;  // staged input rows per channel
constexpr int NWG   = (HH / RPB) * (CHAN / CG) * BATCH;  // 4096
constexpr int NXCD  = 8;
constexpr int CPX   = NWG / NXCD;                        // 512 (4096%8==0)

typedef float vf4 __attribute__((ext_vector_type(4)));
typedef const __attribute__((address_space(1))) void* gas_ptr;
typedef __attribute__((address_space(3))) void* las_ptr;

__global__ __launch_bounds__(256) void dynconv_kernel(
    const float* __restrict__ x,
    const float* __restrict__ ker,
    float* __restrict__ out)
{
    __shared__ float lds[CG][NROW][WW];   // 24 KiB

    // XCD-chunked bijective swizzle, hband fastest
    const int id    = blockIdx.x;
    const int work  = (id & (NXCD - 1)) * CPX + (id >> 3);
    const int hband = work & 63;
    const int cg    = (work >> 6) & 15;
    const int b     = work >> 10;

    const int t  = threadIdx.x;
    const int rb = t >> 6;          // wave id = output row in band
    const int wq = t & 63;          // lane = float4 slot
    const int w0 = wq * 4;
    const int h0 = hband * RPB;
    const int h  = h0 + rb;

    const long cs = (long)HH * WW;
    const float* xb = x   + (((long)b * CHAN + cg * CG) * cs);
    float*       ob = out + (((long)b * CHAN + cg * CG) * cs);

    // ---- (1) issue the 9 ker loads FIRST (oldest in vmcnt queue) ----
    float4 kreg[9];
    const long kbase = (((long)b * 9) * HH + h) * WW + w0;
    #pragma unroll
    for (int j = 0; j < 9; ++j)
        kreg[j] = *reinterpret_cast<const float4*>(ker + kbase + (long)j * HH * WW);

    __builtin_amdgcn_sched_barrier(0);   // keep ker loads above the DMAs

    // ---- (2) issue all 24 row-DMAs (younger; stay in flight during softmax) ----
    #pragma unroll
    for (int k = 0; k < (CG * NROW) / RPB; ++k) {
        const int idx  = k * RPB + rb;
        const int ch   = idx / NROW;
        const int slot = idx % NROW;
        int g = h0 - 1 + slot;
        g = (g < 0) ? 1 : ((g > HH - 1) ? HH - 2 : g);
        const float* gsrc = xb + (long)ch * cs + (long)g * WW + w0;
        __builtin_amdgcn_global_load_lds((gas_ptr)gsrc, (las_ptr)&lds[ch][slot][0], 16, 0, 0);
    }

    __builtin_amdgcn_sched_barrier(0);   // keep DMA issue above the softmax VALU

    // ---- (3) softmax on ker data: waits only vmcnt(24) => DMAs still in flight ----
    float kv[9][4];
    #pragma unroll
    for (int j = 0; j < 9; ++j) {
        kv[j][0] = kreg[j].x; kv[j][1] = kreg[j].y;
        kv[j][2] = kreg[j].z; kv[j][3] = kreg[j].w;
    }
    #pragma unroll
    for (int p = 0; p < 4; ++p) {
        float m = kv[0][p];
        #pragma unroll
        for (int j = 1; j < 9; ++j) m = fmaxf(m, kv[j][p]);
        float s = 0.f;
        #pragma unroll
        for (int j = 0; j < 9; ++j) { kv[j][p] = __expf(kv[j][p] - m); s += kv[j][p]; }
        const float inv = 1.0f / s;
        #pragma unroll
        for (int j = 0; j < 9; ++j) kv[j][p] *= inv;
    }

    __syncthreads();   // drains remaining DMAs, rows visible across waves

    // ---- (4) conv from LDS; halo via cross-lane shuffle ----
    #pragma unroll
    for (int i = 0; i < CG; ++i) {
        float acc0 = 0.f, acc1 = 0.f, acc2 = 0.f, acc3 = 0.f;
        #pragma unroll
        for (int r = 0; r < 3; ++r) {
            const float4 v = *reinterpret_cast<const float4*>(&lds[i][rb + r][w0]);
            float lft = __shfl_up(v.w, 1);
            if (wq == 0)  lft = v.y;     // reflect x[-1] -> x[1]
            float rgt = __shfl_down(v.x, 1);
            if (wq == 63) rgt = v.z;     // reflect x[256] -> x[254]
            const float vals[6] = { lft, v.x, v.y, v.z, v.w, rgt };
            #pragma unroll
            for (int dx = 0; dx < 3; ++dx) {
                const int j = r * 3 + dx;
                acc0 = fmaf(kv[j][0], vals[0 + dx], acc0);
                acc1 = fmaf(kv[j][1], vals[1 + dx], acc1);
                acc2 = fmaf(kv[j][2], vals[2 + dx], acc2);
                acc3 = fmaf(kv[j][3], vals[3 + dx], acc3);
            }
        }
        vf4 o; o.x = acc0; o.y = acc1; o.z = acc2; o.w = acc3;
        __builtin_nontemporal_store(o,
            reinterpret_cast<vf4*>(ob + (long)i * cs + (long)h * WW + w0));
    }
}

extern "C" void kernel_launch(void* const* d_in, const int* in_sizes, int n_in,
                              void* d_out, int out_size, void* d_ws, size_t ws_size,
                              hipStream_t stream) {
    const float* x   = (const float*)d_in[0];
    const float* ker = (const float*)d_in[1];
    float* out = (float*)d_out;

    dynconv_kernel<<<dim3(NWG), dim3(256), 0, stream>>>(x, ker, out);
}